// Round 1
// baseline (144.312 us; speedup 1.0000x reference)
//
#include <hip/hip_runtime.h>
#include <math.h>

#define Bq 2048
#define Nn 1024
#define Dd 128
#define Cc 10
#define BB 8          // batch rows per block
#define NTHREADS 512  // 8 waves; wave w reduces b=w

// d_out layout (floats): [0, B*C) = labels[bmu]; [B*C, B*C+N*C) = activities; last C = counts
#define ACT_OFF (Bq * Cc)
#define CNT_OFF (Bq * Cc + Nn * Cc)

__global__ void som_init(const float* __restrict__ act_in,
                         const int* __restrict__ cnt_in,
                         float* __restrict__ out) {
    int i = blockIdx.x * blockDim.x + threadIdx.x;
    if (i < Nn * Cc) out[ACT_OFF + i] = act_in[i];
    if (i < Cc) out[CNT_OFF + i] = (float)cnt_in[i];
}

__global__ __launch_bounds__(NTHREADS) void som_main(
    const float* __restrict__ x,
    const float* __restrict__ y,
    const float* __restrict__ neurons,
    const float* __restrict__ labels,
    const float* __restrict__ sigma,
    float* __restrict__ out)
{
    __shared__ float xs[BB][Dd];     // 4 KB
    __shared__ float d2s[BB][Nn];    // 32 KB
    __shared__ float bmu_d[BB];
    __shared__ int   bmu_i[BB];
    __shared__ int   clss[BB];

    const int t  = threadIdx.x;
    const int b0 = blockIdx.x * BB;

    // stage x rows (coalesced)
    for (int i = t; i < BB * Dd; i += NTHREADS) {
        xs[i >> 7][i & (Dd - 1)] = x[b0 * Dd + i];
    }
    __syncthreads();

    // each thread owns neurons n0 = t and n1 = t + 512, all BB batch rows
    float acc0[BB], acc1[BB];
    #pragma unroll
    for (int b = 0; b < BB; ++b) { acc0[b] = 0.f; acc1[b] = 0.f; }

    const float4* nr0 = (const float4*)(neurons + t * Dd);
    const float4* nr1 = (const float4*)(neurons + (t + 512) * Dd);

    #pragma unroll 2
    for (int dc = 0; dc < Dd / 4; ++dc) {
        float4 nv0 = nr0[dc];
        float4 nv1 = nr1[dc];
        #pragma unroll
        for (int b = 0; b < BB; ++b) {
            float4 xv = *(const float4*)&xs[b][dc * 4];  // broadcast read
            float d;
            d = xv.x - nv0.x; acc0[b] = fmaf(d, d, acc0[b]);
            d = xv.y - nv0.y; acc0[b] = fmaf(d, d, acc0[b]);
            d = xv.z - nv0.z; acc0[b] = fmaf(d, d, acc0[b]);
            d = xv.w - nv0.w; acc0[b] = fmaf(d, d, acc0[b]);
            d = xv.x - nv1.x; acc1[b] = fmaf(d, d, acc1[b]);
            d = xv.y - nv1.y; acc1[b] = fmaf(d, d, acc1[b]);
            d = xv.z - nv1.z; acc1[b] = fmaf(d, d, acc1[b]);
            d = xv.w - nv1.w; acc1[b] = fmaf(d, d, acc1[b]);
        }
    }

    // spill d2 to LDS for the per-b argmin (stride-1 writes, no conflicts)
    #pragma unroll
    for (int b = 0; b < BB; ++b) {
        d2s[b][t]       = acc0[b];
        d2s[b][t + 512] = acc1[b];
    }
    __syncthreads();

    // wave w does argmin over n for b = w (first-min tie-break like jnp.argmin)
    {
        const int wv = t >> 6, lane = t & 63;
        float best = 3.4e38f; int bidx = 0;
        #pragma unroll
        for (int i = 0; i < Nn / 64; ++i) {
            int idx = lane + i * 64;
            float v = d2s[wv][idx];
            if (v < best) { best = v; bidx = idx; }  // idx increasing -> strict < keeps first
        }
        #pragma unroll
        for (int off = 32; off; off >>= 1) {
            float ov = __shfl_down(best, off);
            int   oi = __shfl_down(bidx, off);
            if (ov < best || (ov == best && oi < bidx)) { best = ov; bidx = oi; }
        }
        if (lane == 0) { bmu_i[wv] = bidx; bmu_d[wv] = sqrtf(best); }
    }

    // cls[b] = argmax_c y[b][c] (strict > keeps first, matching jnp.argmax); histogram
    if (t < BB) {
        const float* yr = y + (long)(b0 + t) * Cc;
        float bv = yr[0]; int bc = 0;
        #pragma unroll
        for (int c = 1; c < Cc; ++c) { float v = yr[c]; if (v > bv) { bv = v; bc = c; } }
        clss[t] = bc;
        atomicAdd(out + CNT_OFF + bc, 1.0f);
    }
    __syncthreads();

    // out rows: labels[bmu[b]]
    for (int i = t; i < BB * Cc; i += NTHREADS) {
        int b = i / Cc, c = i % Cc;
        out[(long)(b0 + b) * Cc + c] = labels[(long)bmu_i[b] * Cc + c];
    }

    // g_norm = exp(-d/sig)/exp(-d_bmu/sig), scatter into activities[:, cls[b]]
    const float sig = sigma[0];
    #pragma unroll
    for (int b = 0; b < BB; ++b) {
        float gb = expf(-bmu_d[b] / sig);
        int   cl = clss[b];
        float g0 = expf(-sqrtf(acc0[b]) / sig);
        float g1 = expf(-sqrtf(acc1[b]) / sig);
        float gn0 = (gb == 0.f) ? 0.f : g0 / gb;
        float gn1 = (gb == 0.f) ? 0.f : g1 / gb;
        atomicAdd(out + ACT_OFF + t * Cc + cl, gn0);
        atomicAdd(out + ACT_OFF + (t + 512) * Cc + cl, gn1);
    }
}

extern "C" void kernel_launch(void* const* d_in, const int* in_sizes, int n_in,
                              void* d_out, int out_size, void* d_ws, size_t ws_size,
                              hipStream_t stream) {
    const float* x       = (const float*)d_in[0];
    const float* y       = (const float*)d_in[1];
    const float* neurons = (const float*)d_in[2];
    const float* labels  = (const float*)d_in[3];
    const float* act     = (const float*)d_in[4];
    const int*   cnt     = (const int*)d_in[5];
    const float* sigma   = (const float*)d_in[6];
    float* out = (float*)d_out;

    som_init<<<(Nn * Cc + 255) / 256, 256, 0, stream>>>(act, cnt, out);
    som_main<<<Bq / BB, NTHREADS, 0, stream>>>(x, y, neurons, labels, sigma, out);
}

// Round 2
// 54.860 us; speedup vs baseline: 2.6305x; 2.6305x over previous
//
#include <hip/hip_runtime.h>
#include <math.h>

#define Bq 2048
#define Nn 1024
#define Dd 128
#define Cc 10
#define BB 8          // batch rows per block
#define NTHREADS 512  // 8 waves
#define NBLK (Bq / BB)               // 256 dist-blocks
#define PART_FLOATS (NBLK * Nn * Cc) // 2.62M floats = 10.5 MB

// d_out layout (floats): [0, B*C) = labels[bmu]; [B*C, B*C+N*C) = activities; last C = counts
#define ACT_OFF (Bq * Cc)
#define CNT_OFF (Bq * Cc + Nn * Cc)

// ---------------- main distance kernel: writes per-block c-major partials ----------------
__global__ __launch_bounds__(NTHREADS) void som_dist(
    const float* __restrict__ x,
    const float* __restrict__ y,
    const float* __restrict__ neurons,
    const float* __restrict__ labels,
    const float* __restrict__ sigma,
    float* __restrict__ out,
    float* __restrict__ ws_p,     // [NBLK][Cc][Nn]
    int*   __restrict__ ws_cls)   // [Bq]
{
    __shared__ float xs[BB][Dd];     // 4 KB
    __shared__ float d2s[BB][Nn];    // 32 KB
    __shared__ float bmu_d[BB];
    __shared__ int   bmu_i[BB];
    __shared__ int   clss[BB];

    const int t  = threadIdx.x;
    const int b0 = blockIdx.x * BB;

    // stage x rows (coalesced)
    for (int i = t; i < BB * Dd; i += NTHREADS) {
        xs[i >> 7][i & (Dd - 1)] = x[b0 * Dd + i];
    }
    __syncthreads();

    // each thread owns neurons n0 = t and n1 = t + 512, all BB batch rows
    float acc0[BB], acc1[BB];
    #pragma unroll
    for (int b = 0; b < BB; ++b) { acc0[b] = 0.f; acc1[b] = 0.f; }

    const float4* nr0 = (const float4*)(neurons + t * Dd);
    const float4* nr1 = (const float4*)(neurons + (t + 512) * Dd);

    #pragma unroll 2
    for (int dc = 0; dc < Dd / 4; ++dc) {
        float4 nv0 = nr0[dc];
        float4 nv1 = nr1[dc];
        #pragma unroll
        for (int b = 0; b < BB; ++b) {
            float4 xv = *(const float4*)&xs[b][dc * 4];  // broadcast read
            float d;
            d = xv.x - nv0.x; acc0[b] = fmaf(d, d, acc0[b]);
            d = xv.y - nv0.y; acc0[b] = fmaf(d, d, acc0[b]);
            d = xv.z - nv0.z; acc0[b] = fmaf(d, d, acc0[b]);
            d = xv.w - nv0.w; acc0[b] = fmaf(d, d, acc0[b]);
            d = xv.x - nv1.x; acc1[b] = fmaf(d, d, acc1[b]);
            d = xv.y - nv1.y; acc1[b] = fmaf(d, d, acc1[b]);
            d = xv.z - nv1.z; acc1[b] = fmaf(d, d, acc1[b]);
            d = xv.w - nv1.w; acc1[b] = fmaf(d, d, acc1[b]);
        }
    }

    // spill d2 to LDS for the per-b argmin
    #pragma unroll
    for (int b = 0; b < BB; ++b) {
        d2s[b][t]       = acc0[b];
        d2s[b][t + 512] = acc1[b];
    }
    __syncthreads();

    // wave w does argmin over n for b = w (first-min tie-break like jnp.argmin)
    {
        const int wv = t >> 6, lane = t & 63;
        float best = 3.4e38f; int bidx = 0;
        #pragma unroll
        for (int i = 0; i < Nn / 64; ++i) {
            int idx = lane + i * 64;
            float v = d2s[wv][idx];
            if (v < best) { best = v; bidx = idx; }
        }
        #pragma unroll
        for (int off = 32; off; off >>= 1) {
            float ov = __shfl_down(best, off);
            int   oi = __shfl_down(bidx, off);
            if (ov < best || (ov == best && oi < bidx)) { best = ov; bidx = oi; }
        }
        if (lane == 0) { bmu_i[wv] = bidx; bmu_d[wv] = sqrtf(best); }
    }

    // cls[b] = argmax_c y[b][c] (strict > keeps first, matching jnp.argmax)
    if (t < BB) {
        const float* yr = y + (long)(b0 + t) * Cc;
        float bv = yr[0]; int bc = 0;
        #pragma unroll
        for (int c = 1; c < Cc; ++c) { float v = yr[c]; if (v > bv) { bv = v; bc = c; } }
        clss[t] = bc;
        ws_cls[b0 + t] = bc;
    }
    __syncthreads();

    // out rows: labels[bmu[b]]
    for (int i = t; i < BB * Cc; i += NTHREADS) {
        int b = i / Cc, c = i % Cc;
        out[(long)(b0 + b) * Cc + c] = labels[(long)bmu_i[b] * Cc + c];
    }

    // fold this block's 8 b's into per-class partials (registers, static indices)
    const float sig = sigma[0];
    float accA[Cc], accB[Cc];
    #pragma unroll
    for (int c = 0; c < Cc; ++c) { accA[c] = 0.f; accB[c] = 0.f; }

    #pragma unroll
    for (int b = 0; b < BB; ++b) {
        float gb = expf(-bmu_d[b] / sig);
        int   cl = clss[b];
        float g0 = expf(-sqrtf(acc0[b]) / sig);
        float g1 = expf(-sqrtf(acc1[b]) / sig);
        float gn0 = (gb == 0.f) ? 0.f : g0 / gb;
        float gn1 = (gb == 0.f) ? 0.f : g1 / gb;
        #pragma unroll
        for (int c = 0; c < Cc; ++c) {
            accA[c] += (cl == c) ? gn0 : 0.f;
            accB[c] += (cl == c) ? gn1 : 0.f;
        }
    }

    // c-major partial write: coalesced across t
    float* pb = ws_p + (long)blockIdx.x * (Nn * Cc);
    #pragma unroll
    for (int c = 0; c < Cc; ++c) {
        pb[c * Nn + t]       = accA[c];
        pb[c * Nn + t + 512] = accB[c];
    }
}

// ---------------- final reduction: no atomics, fully deterministic ----------------
__global__ __launch_bounds__(256) void som_fin(
    const float* __restrict__ act_in,
    const int*   __restrict__ cnt_in,
    const float* __restrict__ ws_p,
    const int*   __restrict__ ws_cls,
    float* __restrict__ out)
{
    if (blockIdx.x < 40) {
        const int j = blockIdx.x * 256 + threadIdx.x;  // j = c*Nn + n
        const int c = j >> 10;
        const int n = j & (Nn - 1);
        float s0 = 0.f, s1 = 0.f, s2 = 0.f, s3 = 0.f;
        for (int k = 0; k < NBLK; k += 4) {
            s0 += ws_p[(long)(k + 0) * (Nn * Cc) + j];
            s1 += ws_p[(long)(k + 1) * (Nn * Cc) + j];
            s2 += ws_p[(long)(k + 2) * (Nn * Cc) + j];
            s3 += ws_p[(long)(k + 3) * (Nn * Cc) + j];
        }
        out[ACT_OFF + n * Cc + c] = act_in[n * Cc + c] + ((s0 + s1) + (s2 + s3));
    } else {
        // class histogram for counts
        __shared__ int hist[Cc];
        if (threadIdx.x < Cc) hist[threadIdx.x] = 0;
        __syncthreads();
        for (int b = threadIdx.x; b < Bq; b += 256) atomicAdd(&hist[ws_cls[b]], 1);
        __syncthreads();
        if (threadIdx.x < Cc)
            out[CNT_OFF + threadIdx.x] = (float)(cnt_in[threadIdx.x] + hist[threadIdx.x]);
    }
}

// ---------------- fallback path (atomic-based, known-good) ----------------
__global__ void som_init(const float* __restrict__ act_in,
                         const int* __restrict__ cnt_in,
                         float* __restrict__ out) {
    int i = blockIdx.x * blockDim.x + threadIdx.x;
    if (i < Nn * Cc) out[ACT_OFF + i] = act_in[i];
    if (i < Cc) out[CNT_OFF + i] = (float)cnt_in[i];
}

__global__ __launch_bounds__(NTHREADS) void som_main(
    const float* __restrict__ x,
    const float* __restrict__ y,
    const float* __restrict__ neurons,
    const float* __restrict__ labels,
    const float* __restrict__ sigma,
    float* __restrict__ out)
{
    __shared__ float xs[BB][Dd];
    __shared__ float d2s[BB][Nn];
    __shared__ float bmu_d[BB];
    __shared__ int   bmu_i[BB];
    __shared__ int   clss[BB];

    const int t  = threadIdx.x;
    const int b0 = blockIdx.x * BB;

    for (int i = t; i < BB * Dd; i += NTHREADS)
        xs[i >> 7][i & (Dd - 1)] = x[b0 * Dd + i];
    __syncthreads();

    float acc0[BB], acc1[BB];
    #pragma unroll
    for (int b = 0; b < BB; ++b) { acc0[b] = 0.f; acc1[b] = 0.f; }

    const float4* nr0 = (const float4*)(neurons + t * Dd);
    const float4* nr1 = (const float4*)(neurons + (t + 512) * Dd);

    #pragma unroll 2
    for (int dc = 0; dc < Dd / 4; ++dc) {
        float4 nv0 = nr0[dc];
        float4 nv1 = nr1[dc];
        #pragma unroll
        for (int b = 0; b < BB; ++b) {
            float4 xv = *(const float4*)&xs[b][dc * 4];
            float d;
            d = xv.x - nv0.x; acc0[b] = fmaf(d, d, acc0[b]);
            d = xv.y - nv0.y; acc0[b] = fmaf(d, d, acc0[b]);
            d = xv.z - nv0.z; acc0[b] = fmaf(d, d, acc0[b]);
            d = xv.w - nv0.w; acc0[b] = fmaf(d, d, acc0[b]);
            d = xv.x - nv1.x; acc1[b] = fmaf(d, d, acc1[b]);
            d = xv.y - nv1.y; acc1[b] = fmaf(d, d, acc1[b]);
            d = xv.z - nv1.z; acc1[b] = fmaf(d, d, acc1[b]);
            d = xv.w - nv1.w; acc1[b] = fmaf(d, d, acc1[b]);
        }
    }

    #pragma unroll
    for (int b = 0; b < BB; ++b) {
        d2s[b][t]       = acc0[b];
        d2s[b][t + 512] = acc1[b];
    }
    __syncthreads();

    {
        const int wv = t >> 6, lane = t & 63;
        float best = 3.4e38f; int bidx = 0;
        #pragma unroll
        for (int i = 0; i < Nn / 64; ++i) {
            int idx = lane + i * 64;
            float v = d2s[wv][idx];
            if (v < best) { best = v; bidx = idx; }
        }
        #pragma unroll
        for (int off = 32; off; off >>= 1) {
            float ov = __shfl_down(best, off);
            int   oi = __shfl_down(bidx, off);
            if (ov < best || (ov == best && oi < bidx)) { best = ov; bidx = oi; }
        }
        if (lane == 0) { bmu_i[wv] = bidx; bmu_d[wv] = sqrtf(best); }
    }

    if (t < BB) {
        const float* yr = y + (long)(b0 + t) * Cc;
        float bv = yr[0]; int bc = 0;
        #pragma unroll
        for (int c = 1; c < Cc; ++c) { float v = yr[c]; if (v > bv) { bv = v; bc = c; } }
        clss[t] = bc;
        atomicAdd(out + CNT_OFF + bc, 1.0f);
    }
    __syncthreads();

    for (int i = t; i < BB * Cc; i += NTHREADS) {
        int b = i / Cc, c = i % Cc;
        out[(long)(b0 + b) * Cc + c] = labels[(long)bmu_i[b] * Cc + c];
    }

    const float sig = sigma[0];
    #pragma unroll
    for (int b = 0; b < BB; ++b) {
        float gb = expf(-bmu_d[b] / sig);
        int   cl = clss[b];
        float g0 = expf(-sqrtf(acc0[b]) / sig);
        float g1 = expf(-sqrtf(acc1[b]) / sig);
        float gn0 = (gb == 0.f) ? 0.f : g0 / gb;
        float gn1 = (gb == 0.f) ? 0.f : g1 / gb;
        atomicAdd(out + ACT_OFF + t * Cc + cl, gn0);
        atomicAdd(out + ACT_OFF + (t + 512) * Cc + cl, gn1);
    }
}

extern "C" void kernel_launch(void* const* d_in, const int* in_sizes, int n_in,
                              void* d_out, int out_size, void* d_ws, size_t ws_size,
                              hipStream_t stream) {
    const float* x       = (const float*)d_in[0];
    const float* y       = (const float*)d_in[1];
    const float* neurons = (const float*)d_in[2];
    const float* labels  = (const float*)d_in[3];
    const float* act     = (const float*)d_in[4];
    const int*   cnt     = (const int*)d_in[5];
    const float* sigma   = (const float*)d_in[6];
    float* out = (float*)d_out;

    const size_t need = (size_t)PART_FLOATS * 4 + (size_t)Bq * 4;
    if (ws_size >= need) {
        float* ws_p   = (float*)d_ws;
        int*   ws_cls = (int*)((float*)d_ws + PART_FLOATS);
        som_dist<<<NBLK, NTHREADS, 0, stream>>>(x, y, neurons, labels, sigma, out, ws_p, ws_cls);
        som_fin<<<41, 256, 0, stream>>>(act, cnt, ws_p, ws_cls, out);
    } else {
        som_init<<<(Nn * Cc + 255) / 256, 256, 0, stream>>>(act, cnt, out);
        som_main<<<Bq / BB, NTHREADS, 0, stream>>>(x, y, neurons, labels, sigma, out);
    }
}